// Round 1
// baseline (936.313 us; speedup 1.0000x reference)
//
#include <hip/hip_runtime.h>
#include <hip/hip_bf16.h>

// FrozenBNBEmbedding: dequantize-blockwise (int8 codes -> fp32 via 256-entry LUT,
// per-4096-block absmax scale) fused with embedding gather.
// DIM == BLOCK == 4096  =>  one absmax scale per vocab row.

#define DIM 4096

__global__ __launch_bounds__(256) void bnb_embed_kernel(
    const int* __restrict__ tokens,    // [n_tokens] token ids
    const int* __restrict__ weight,    // [VOCAB, DIM] int8 codes stored as int32
    const float* __restrict__ absmax,  // [VOCAB] per-row scale (n_blocks == VOCAB here)
    const float* __restrict__ code,    // [256] LUT
    float* __restrict__ out,           // [n_tokens, DIM] fp32
    int n_tokens)
{
    __shared__ float lut[256];
    lut[threadIdx.x] = code[threadIdx.x];
    __syncthreads();

    const int tokIdx = blockIdx.x;
    if (tokIdx >= n_tokens) return;

    const int t = tokens[tokIdx];
    const float scale = absmax[t];

    const int4* __restrict__ wrow = (const int4*)(weight + (size_t)t * DIM);
    float4* __restrict__ orow = (float4*)(out + (size_t)tokIdx * DIM);

    // 4096 elems / 4 per vec = 1024 int4 groups; 256 threads -> 4 groups/thread.
#pragma unroll
    for (int i = 0; i < 4; ++i) {
        const int idx = threadIdx.x + i * 256;
        const int4 q = wrow[idx];
        float4 o;
        o.x = lut[q.x & 255] * scale;
        o.y = lut[q.y & 255] * scale;
        o.z = lut[q.z & 255] * scale;
        o.w = lut[q.w & 255] * scale;
        orow[idx] = o;
    }
}

extern "C" void kernel_launch(void* const* d_in, const int* in_sizes, int n_in,
                              void* d_out, int out_size, void* d_ws, size_t ws_size,
                              hipStream_t stream)
{
    const int*   tokens = (const int*)d_in[0];    // [4, 2048] int32
    const int*   weight = (const int*)d_in[1];    // [50400, 4096] int32
    const float* absmax = (const float*)d_in[2];  // [50400] fp32
    const float* code   = (const float*)d_in[3];  // [256] fp32
    float*       out    = (float*)d_out;          // [4, 2048, 4096] fp32

    const int n_tokens = in_sizes[0];             // 8192
    bnb_embed_kernel<<<n_tokens, 256, 0, stream>>>(tokens, weight, absmax, code, out, n_tokens);
}